// Round 7
// baseline (202.569 us; speedup 1.0000x reference)
//
#include <hip/hip_runtime.h>
#include <math.h>

// Hyperbolic GCN conv (Poincare ball, c=1):
//  h = proj(x W^T); h = proj(mobius_add(h, expmap0(bias)))
//  s = p2k(h); lamb = lorenz(s); g = deg^-1/2 * lamb
//  s_out[i] = (sum_{j in N(i)+self} g[j] s[j]) / (sum g[j])   [dinv[i] cancels]
//  out = leaky_relu(k2p(s_out))
// s kept in f32: k2p denominator amplifies ns noise for boundary nodes.
// CSR build: ONE atomic pass (deg+pos), then scan, then atomic-free placement.

#define EPS_B 4e-3f
#define MINN 1e-15f

typedef __bf16 bf16_t;
typedef __attribute__((ext_vector_type(8))) __bf16 bf16x8;
typedef __attribute__((ext_vector_type(4))) __bf16 bf16x4;
typedef __attribute__((ext_vector_type(4))) float f32x4;

// ---------------- degree + slot in one atomic pass ----------------
__global__ __launch_bounds__(256) void k_deg2(const int* __restrict__ row,
                                              int* __restrict__ cnt,
                                              int* __restrict__ pos, int E) {
    int e = blockIdx.x * 256 + threadIdx.x;
    if (e < E) pos[e] = atomicAdd(&cnt[row[e]], 1);
}

// ---------------- scan (3 kernels, 1024-wide) ----------------
__global__ __launch_bounds__(1024) void k_bsum(const int* __restrict__ cnt,
                                               int* __restrict__ bsum, int n) {
    __shared__ int sd[1024];
    int t = threadIdx.x, idx = blockIdx.x * 1024 + t;
    sd[t] = idx < n ? cnt[idx] : 0;
    __syncthreads();
    for (int s = 512; s > 0; s >>= 1) {
        if (t < s) sd[t] += sd[t + s];
        __syncthreads();
    }
    if (t == 0) bsum[blockIdx.x] = sd[0];
}

__global__ __launch_bounds__(128) void k_scan_bsum(int* bsum, int nb) {
    __shared__ int sd[128];
    int t = threadIdx.x;
    int v = t < nb ? bsum[t] : 0;
    sd[t] = v;
    __syncthreads();
    for (int off = 1; off < 128; off <<= 1) {
        int x = (t >= off) ? sd[t - off] : 0;
        __syncthreads();
        sd[t] += x;
        __syncthreads();
    }
    if (t < nb) bsum[t] = sd[t] - v;  // exclusive
}

__global__ __launch_bounds__(1024) void k_rowstart(const int* __restrict__ cnt,
                                                   const int* __restrict__ bsum,
                                                   int* __restrict__ rowst, int n) {
    __shared__ int sd[1024];
    int t = threadIdx.x, idx = blockIdx.x * 1024 + t;
    int v = idx < n ? cnt[idx] : 0;
    sd[t] = v;
    __syncthreads();
    for (int off = 1; off < 1024; off <<= 1) {
        int x = (t >= off) ? sd[t - off] : 0;
        __syncthreads();
        sd[t] += x;
        __syncthreads();
    }
    if (idx < n) rowst[idx] = sd[t] - v + bsum[blockIdx.x];
}

// ---------------- CSR placement (no atomics) ----------------
__global__ __launch_bounds__(256) void k_place(const int* __restrict__ row,
                                               const int* __restrict__ col,
                                               const int* __restrict__ rowst,
                                               const int* __restrict__ pos,
                                               int* __restrict__ csr, int E) {
    int e = blockIdx.x * 256 + threadIdx.x;
    if (e < E) csr[rowst[row[e]] + pos[e]] = col[e];
}

// ---------------- GEMM (split-bf16 MFMA) + hyperbolic transforms ----------------
// R4-proven structure: W hi/lo staged in LDS as bf16 [128][136] per block.
// mfma_f32_16x16x32_bf16: A lane l holds A[l&15][8*(l>>4)+i];
// B lane l holds B[8*(l>>4)+i][l&15]; D lane l reg r holds D[4*(l>>4)+r][l&15].
#define WP 136  // bf16 pitch for W tiles
#define HP 140  // f32 pitch for h overlay

__global__ __launch_bounds__(256, 2) void k_gemm(const float* __restrict__ x,
                                                 const float* __restrict__ W,
                                                 const float* __restrict__ bias,
                                                 const int* __restrict__ cnt,
                                                 float* __restrict__ sbuf,
                                                 float* __restrict__ gbuf, int N) {
    __shared__ __align__(16) unsigned char smem[128 * WP * 2 * 2];  // 69632 B
    bf16_t* Whi = (bf16_t*)smem;
    bf16_t* Wlo = Whi + 128 * WP;
    float* h_s = (float*)smem;  // overlay after MFMA: [64][HP] f32 = 35840 B
    __shared__ float hb_s[128];

    const int t = threadIdx.x;
    const int base = blockIdx.x * 64;
    const float MAXN = 1.0f - EPS_B;

    // hyp bias = expmap0(bias); ||b||^2 via 2 reads + wave shfl reduce
    if (t < 128) hb_s[t] = bias[t];
    __syncthreads();
    const int l6 = t & 63;
    float b0 = hb_s[2 * l6], b1 = hb_s[2 * l6 + 1];
    float bn2 = b0 * b0 + b1 * b1;
#pragma unroll
    for (int m = 1; m < 64; m <<= 1) bn2 += __shfl_xor(bn2, m);
    float un = fmaxf(sqrtf(bn2), MINN);
    float th = tanhf(un);
    float y2 = th * th;
    __syncthreads();  // all bn2 reads done before rescale
    if (t < 128) hb_s[t] *= th / un;
    // (staging __syncthreads below orders this write before epilogue reads)

    // stage W as hi/lo bf16
#pragma unroll
    for (int i2 = 0; i2 < 16; ++i2) {
        int idx = t + 256 * i2;  // 0..4095 float4s
        int r = idx >> 5, c4 = idx & 31;
        float4 v = ((const float4*)W)[idx];
        bf16_t h0 = (bf16_t)v.x, h1 = (bf16_t)v.y, h2 = (bf16_t)v.z, h3 = (bf16_t)v.w;
        bf16x4 hv = {h0, h1, h2, h3};
        bf16x4 lv = {(bf16_t)(v.x - (float)h0), (bf16_t)(v.y - (float)h1),
                     (bf16_t)(v.z - (float)h2), (bf16_t)(v.w - (float)h3)};
        *(bf16x4*)&Whi[r * WP + 4 * c4] = hv;
        *(bf16x4*)&Wlo[r * WP + 4 * c4] = lv;
    }

    // A fragments from global (hi/lo)
    const int w = t >> 6, l = t & 63;
    const int mrow = l & 15, kq = l >> 4;
    const int gn = base + 16 * w + mrow;
    bf16x8 ahi[4], alo[4];
    {
        const float4* xr4 = (const float4*)(x + (size_t)gn * 128);
#pragma unroll
        for (int kt = 0; kt < 4; ++kt) {
            float4 v0 = make_float4(0.f, 0.f, 0.f, 0.f), v1 = v0;
            if (gn < N) {
                v0 = xr4[8 * kt + 2 * kq];
                v1 = xr4[8 * kt + 2 * kq + 1];
            }
            float f[8] = {v0.x, v0.y, v0.z, v0.w, v1.x, v1.y, v1.z, v1.w};
#pragma unroll
            for (int i = 0; i < 8; ++i) {
                bf16_t h = (bf16_t)f[i];
                ahi[kt][i] = h;
                alo[kt][i] = (bf16_t)(f[i] - (float)h);
            }
        }
    }
    __syncthreads();

    f32x4 acc[8];
#pragma unroll
    for (int nt = 0; nt < 8; ++nt) acc[nt] = (f32x4){0.f, 0.f, 0.f, 0.f};

#pragma unroll
    for (int nt = 0; nt < 8; ++nt) {
#pragma unroll
        for (int kt = 0; kt < 4; ++kt) {
            bf16x8 bhi = *(bf16x8*)&Whi[(16 * nt + mrow) * WP + 32 * kt + 8 * kq];
            bf16x8 blo = *(bf16x8*)&Wlo[(16 * nt + mrow) * WP + 32 * kt + 8 * kq];
            acc[nt] = __builtin_amdgcn_mfma_f32_16x16x32_bf16(ahi[kt], bhi, acc[nt], 0, 0, 0);
            acc[nt] = __builtin_amdgcn_mfma_f32_16x16x32_bf16(alo[kt], bhi, acc[nt], 0, 0, 0);
            acc[nt] = __builtin_amdgcn_mfma_f32_16x16x32_bf16(ahi[kt], blo, acc[nt], 0, 0, 0);
        }
    }
    __syncthreads();  // all waves done reading W before overlay

    // write h to LDS overlay, re-map to 4 threads/node
#pragma unroll
    for (int nt = 0; nt < 8; ++nt)
#pragma unroll
        for (int r = 0; r < 4; ++r)
            h_s[(16 * w + 4 * kq + r) * HP + 16 * nt + mrow] = acc[nt][r];
    __syncthreads();

    const int node = t >> 2, lg = t & 3;
    const int gn2 = base + node;
    float h[32], hb[32];
#pragma unroll
    for (int q = 0; q < 8; ++q) {
        float4 v = *(const float4*)&h_s[node * HP + lg * 32 + 4 * q];
        h[4 * q] = v.x; h[4 * q + 1] = v.y; h[4 * q + 2] = v.z; h[4 * q + 3] = v.w;
        float4 b = *(const float4*)&hb_s[lg * 32 + 4 * q];
        hb[4 * q] = b.x; hb[4 * q + 1] = b.y; hb[4 * q + 2] = b.z; hb[4 * q + 3] = b.w;
    }
    // proj(h)
    float x2 = 0.f;
#pragma unroll
    for (int d = 0; d < 32; ++d) x2 += h[d] * h[d];
    x2 += __shfl_xor(x2, 1); x2 += __shfl_xor(x2, 2);
    float nrm = sqrtf(x2);
    float sc = nrm > MAXN ? MAXN / nrm : 1.f;
#pragma unroll
    for (int d = 0; d < 32; ++d) h[d] *= sc;
    x2 *= sc * sc;
    // mobius_add(h, hb)
    float xy = 0.f;
#pragma unroll
    for (int d = 0; d < 32; ++d) xy += h[d] * hb[d];
    xy += __shfl_xor(xy, 1); xy += __shfl_xor(xy, 2);
    float ca = 1.f + 2.f * xy + y2;
    float cb = 1.f - x2;
    float den = 1.f + 2.f * xy + x2 * y2;
    float invd = 1.f / fmaxf(den, MINN);
    float m2 = 0.f;
#pragma unroll
    for (int d = 0; d < 32; ++d) {
        float v = (ca * h[d] + cb * hb[d]) * invd;
        h[d] = v;
        m2 += v * v;
    }
    m2 += __shfl_xor(m2, 1); m2 += __shfl_xor(m2, 2);
    // proj again
    float nrm2 = sqrtf(m2);
    float sc2 = nrm2 > MAXN ? MAXN / nrm2 : 1.f;
    m2 *= sc2 * sc2;
    // p2k + lorenz
    float pf = 2.f / (1.f + m2);
    float ns = pf * pf * m2;
    float lamb = rsqrtf(fmaxf(1.f - ns, MINN));
    if (gn2 < N) {
        float* dst = sbuf + (size_t)gn2 * 128 + lg * 32;
        float f = pf * sc2;
#pragma unroll
        for (int q = 0; q < 8; ++q)
            *(float4*)&dst[4 * q] = make_float4(f * h[4 * q], f * h[4 * q + 1],
                                                f * h[4 * q + 2], f * h[4 * q + 3]);
        if (lg == 0) gbuf[gn2] = lamb * rsqrtf((float)(cnt[gn2] + 1));
    }
}

// ---------------- aggregation + k2p + leaky_relu ----------------
// one wave per node. Per 64-edge batch: lane preloads index jv AND weight gv;
// tw via one wave-reduce; gather loop is BRANCHLESS — 8 edges/iter via
// quarter-waves (16 lanes x 2 float4 = 512 B/edge, 4 loads/lane in flight).
// Tail lanes have jv=0, gv=0: they gather row 0 (L2-hot) and FMA by 0 (exact).
// NOTE: __shfl must execute with FULL exec (R3 bug).
__global__ __launch_bounds__(256) void k_agg(const float* __restrict__ s,
                                             const float* __restrict__ g,
                                             const int* __restrict__ rowst,
                                             const int* __restrict__ cnt,
                                             const int* __restrict__ csr,
                                             float* __restrict__ out, int N) {
    const int wid = threadIdx.x >> 6, lane = threadIdx.x & 63;
    const int q = lane >> 4, ql = lane & 15;
    const int i = blockIdx.x * 4 + wid;
    if (i >= N) return;

    float a[8] = {0.f, 0.f, 0.f, 0.f, 0.f, 0.f, 0.f, 0.f};
    float tw = g[i];  // self-loop weight (all lanes)
    if (q == 0) {     // self-loop vector term on quarter 0 (counted once)
        const float* sr = s + (size_t)i * 128 + ql * 8;
        float4 v0 = *(const float4*)sr;
        float4 v1 = *(const float4*)(sr + 4);
        a[0] = tw * v0.x; a[1] = tw * v0.y; a[2] = tw * v0.z; a[3] = tw * v0.w;
        a[4] = tw * v1.x; a[5] = tw * v1.y; a[6] = tw * v1.z; a[7] = tw * v1.w;
    }
    const int st = rowst[i];
    const int c = cnt[i];
    for (int bs = 0; bs < c; bs += 64) {
        int rem = c - bs;
        if (rem > 64) rem = 64;
        int jv = 0;
        float gv = 0.f;
        if (lane < rem) {
            jv = csr[st + bs + lane];
            gv = g[jv];
        }
        // batch weight sum (one reduce instead of per-edge accumulation)
        float tws = gv;
#pragma unroll
        for (int m = 1; m < 64; m <<= 1) tws += __shfl_xor(tws, m);
        tw += tws;
        for (int e = 0; e < rem; e += 8) {
            int j0 = __shfl(jv, e + q);          // full-exec shfl
            int j1 = __shfl(jv, e + 4 + q);      // e<=56, so e+4+q<=63
            float gj0 = __shfl(gv, e + q);
            float gj1 = __shfl(gv, e + 4 + q);
            const float* r0 = s + (size_t)j0 * 128 + ql * 8;
            const float* r1 = s + (size_t)j1 * 128 + ql * 8;
            float4 v0a = *(const float4*)r0;
            float4 v0b = *(const float4*)(r0 + 4);
            float4 v1a = *(const float4*)r1;
            float4 v1b = *(const float4*)(r1 + 4);
            a[0] = fmaf(gj0, v0a.x, a[0]); a[1] = fmaf(gj0, v0a.y, a[1]);
            a[2] = fmaf(gj0, v0a.z, a[2]); a[3] = fmaf(gj0, v0a.w, a[3]);
            a[4] = fmaf(gj0, v0b.x, a[4]); a[5] = fmaf(gj0, v0b.y, a[5]);
            a[6] = fmaf(gj0, v0b.z, a[6]); a[7] = fmaf(gj0, v0b.w, a[7]);
            a[0] = fmaf(gj1, v1a.x, a[0]); a[1] = fmaf(gj1, v1a.y, a[1]);
            a[2] = fmaf(gj1, v1a.z, a[2]); a[3] = fmaf(gj1, v1a.w, a[3]);
            a[4] = fmaf(gj1, v1b.x, a[4]); a[5] = fmaf(gj1, v1b.y, a[5]);
            a[6] = fmaf(gj1, v1b.z, a[6]); a[7] = fmaf(gj1, v1b.w, a[7]);
        }
    }
    // combine the 4 quarter-wave partial sums (lanes with equal ql)
#pragma unroll
    for (int d = 0; d < 8; ++d) {
        a[d] += __shfl_xor(a[d], 16);
        a[d] += __shfl_xor(a[d], 32);
    }

    float inv = 1.f / tw;
    float o[8];
    float ns = 0.f;
#pragma unroll
    for (int d = 0; d < 8; ++d) {
        o[d] = a[d] * inv;
        ns += o[d] * o[d];
    }
    ns += __shfl_xor(ns, 1); ns += __shfl_xor(ns, 2);
    ns += __shfl_xor(ns, 4); ns += __shfl_xor(ns, 8);
    float den = 1.f + sqrtf(fmaxf(1.f - ns, MINN));
    float id = 1.f / den;
#pragma unroll
    for (int d = 0; d < 8; ++d) {
        float v = o[d] * id;
        o[d] = v >= 0.f ? v : 0.01f * v;
    }
    if (lane < 32) {  // 32 lanes x 16B = full 512B coalesced row store
        float4 v = make_float4(o[4 * q], o[4 * q + 1], o[4 * q + 2], o[4 * q + 3]);
        *(float4*)(out + (size_t)i * 128 + ql * 8 + 4 * q) = v;
    }
}

extern "C" void kernel_launch(void* const* d_in, const int* in_sizes, int n_in,
                              void* d_out, int out_size, void* d_ws, size_t ws_size,
                              hipStream_t stream) {
    const float* x    = (const float*)d_in[0];
    const float* W    = (const float*)d_in[1];
    const float* bias = (const float*)d_in[2];
    const int*   ei   = (const int*)d_in[3];  // [2,E] int32

    const int N = in_sizes[0] / 128;
    const int E = in_sizes[3] / 2;
    const int* row = ei;
    const int* col = ei + E;

    // workspace carve
    float*  g_buf  = (float*)d_ws;                 // N
    int*    cnt    = (int*)(g_buf + N);            // N
    int*    rowst  = cnt + N;                      // N
    int*    pos    = rowst + N;                    // E
    int*    csr    = pos + E;                      // E
    int*    bsum   = csr + E;                      // <=128
    float*  s_buf  = (float*)(bsum + 128);         // N*128 f32

    hipMemsetAsync(cnt, 0, (size_t)N * sizeof(int), stream);

    const int nb = (N + 1023) / 1024;  // 98 <= 128
    k_deg2<<<(E + 255) / 256, 256, 0, stream>>>(row, cnt, pos, E);
    k_bsum<<<nb, 1024, 0, stream>>>(cnt, bsum, N);
    k_scan_bsum<<<1, 128, 0, stream>>>(bsum, nb);
    k_rowstart<<<nb, 1024, 0, stream>>>(cnt, bsum, rowst, N);
    k_place<<<(E + 255) / 256, 256, 0, stream>>>(row, col, rowst, pos, csr, E);
    k_gemm<<<(N + 63) / 64, 256, 0, stream>>>(x, W, bias, cnt, s_buf, g_buf, N);
    k_agg<<<(N + 3) / 4, 256, 0, stream>>>(s_buf, g_buf, rowst, cnt, csr,
                                           (float*)d_out, N);
}

// Round 8
// 186.641 us; speedup vs baseline: 1.0853x; 1.0853x over previous
//
#include <hip/hip_runtime.h>
#include <math.h>

// Hyperbolic GCN conv (Poincare ball, c=1):
//  h = proj(x W^T); h = proj(mobius_add(h, expmap0(bias)))
//  s = p2k(h); lamb = lorenz(s); g = deg^-1/2 * lamb
//  s_out[i] = (sum_{j in N(i)+self} g[j] s[j]) / (sum g[j])   [dinv[i] cancels]
//  out = leaky_relu(k2p(s_out))
// s stored in BF16 for the gather (halves the L2-miss traffic that bounds
// k_agg). The k2p denominator 1/(1+sqrt(1-ns)) amplifies ns error ~150x ONLY
// for isolated (deg-0) nodes (s_out == s_i, ns ~ 0.9999); for those we use a
// per-node f32 ns stored by k_gemm. Neighbored nodes have random-direction
// means (ns <~ 0.7) -> amplification < 1.5, bf16 noise harmless.

#define EPS_B 4e-3f
#define MINN 1e-15f

typedef __bf16 bf16_t;
typedef __attribute__((ext_vector_type(8))) __bf16 bf16x8;
typedef __attribute__((ext_vector_type(4))) __bf16 bf16x4;
typedef __attribute__((ext_vector_type(4))) float f32x4;

// ---------------- degree + slot in one atomic pass ----------------
__global__ __launch_bounds__(256) void k_deg2(const int* __restrict__ row,
                                              int* __restrict__ cnt,
                                              int* __restrict__ pos, int E) {
    int e = blockIdx.x * 256 + threadIdx.x;
    if (e < E) pos[e] = atomicAdd(&cnt[row[e]], 1);
}

// ---------------- scan (3 kernels, 1024-wide) ----------------
__global__ __launch_bounds__(1024) void k_bsum(const int* __restrict__ cnt,
                                               int* __restrict__ bsum, int n) {
    __shared__ int sd[1024];
    int t = threadIdx.x, idx = blockIdx.x * 1024 + t;
    sd[t] = idx < n ? cnt[idx] : 0;
    __syncthreads();
    for (int s = 512; s > 0; s >>= 1) {
        if (t < s) sd[t] += sd[t + s];
        __syncthreads();
    }
    if (t == 0) bsum[blockIdx.x] = sd[0];
}

__global__ __launch_bounds__(128) void k_scan_bsum(int* bsum, int nb) {
    __shared__ int sd[128];
    int t = threadIdx.x;
    int v = t < nb ? bsum[t] : 0;
    sd[t] = v;
    __syncthreads();
    for (int off = 1; off < 128; off <<= 1) {
        int x = (t >= off) ? sd[t - off] : 0;
        __syncthreads();
        sd[t] += x;
        __syncthreads();
    }
    if (t < nb) bsum[t] = sd[t] - v;  // exclusive
}

__global__ __launch_bounds__(1024) void k_rowstart(const int* __restrict__ cnt,
                                                   const int* __restrict__ bsum,
                                                   int* __restrict__ rowst, int n) {
    __shared__ int sd[1024];
    int t = threadIdx.x, idx = blockIdx.x * 1024 + t;
    int v = idx < n ? cnt[idx] : 0;
    sd[t] = v;
    __syncthreads();
    for (int off = 1; off < 1024; off <<= 1) {
        int x = (t >= off) ? sd[t - off] : 0;
        __syncthreads();
        sd[t] += x;
        __syncthreads();
    }
    if (idx < n) rowst[idx] = sd[t] - v + bsum[blockIdx.x];
}

// ---------------- CSR placement (no atomics) ----------------
__global__ __launch_bounds__(256) void k_place(const int* __restrict__ row,
                                               const int* __restrict__ col,
                                               const int* __restrict__ rowst,
                                               const int* __restrict__ pos,
                                               int* __restrict__ csr, int E) {
    int e = blockIdx.x * 256 + threadIdx.x;
    if (e < E) csr[rowst[row[e]] + pos[e]] = col[e];
}

// ---------------- GEMM (split-bf16 MFMA) + hyperbolic transforms ----------------
// R4-proven structure: W hi/lo staged in LDS as bf16 [128][136] per block.
// mfma_f32_16x16x32_bf16: A lane l holds A[l&15][8*(l>>4)+i];
// B lane l holds B[8*(l>>4)+i][l&15]; D lane l reg r holds D[4*(l>>4)+r][l&15].
#define WP 136  // bf16 pitch for W tiles
#define HP 140  // f32 pitch for h overlay

__global__ __launch_bounds__(256, 2) void k_gemm(const float* __restrict__ x,
                                                 const float* __restrict__ W,
                                                 const float* __restrict__ bias,
                                                 const int* __restrict__ cnt,
                                                 bf16_t* __restrict__ sbuf,
                                                 float* __restrict__ nsbuf,
                                                 float* __restrict__ gbuf, int N) {
    __shared__ __align__(16) unsigned char smem[128 * WP * 2 * 2];  // 69632 B
    bf16_t* Whi = (bf16_t*)smem;
    bf16_t* Wlo = Whi + 128 * WP;
    float* h_s = (float*)smem;  // overlay after MFMA: [64][HP] f32 = 35840 B
    __shared__ float hb_s[128];

    const int t = threadIdx.x;
    const int base = blockIdx.x * 64;
    const float MAXN = 1.0f - EPS_B;

    // hyp bias = expmap0(bias); ||b||^2 via 2 reads + wave shfl reduce
    if (t < 128) hb_s[t] = bias[t];
    __syncthreads();
    const int l6 = t & 63;
    float b0 = hb_s[2 * l6], b1 = hb_s[2 * l6 + 1];
    float bn2 = b0 * b0 + b1 * b1;
#pragma unroll
    for (int m = 1; m < 64; m <<= 1) bn2 += __shfl_xor(bn2, m);
    float un = fmaxf(sqrtf(bn2), MINN);
    float th = tanhf(un);
    float y2 = th * th;
    __syncthreads();  // all bn2 reads done before rescale
    if (t < 128) hb_s[t] *= th / un;

    // stage W as hi/lo bf16
#pragma unroll
    for (int i2 = 0; i2 < 16; ++i2) {
        int idx = t + 256 * i2;  // 0..4095 float4s
        int r = idx >> 5, c4 = idx & 31;
        float4 v = ((const float4*)W)[idx];
        bf16_t h0 = (bf16_t)v.x, h1 = (bf16_t)v.y, h2 = (bf16_t)v.z, h3 = (bf16_t)v.w;
        bf16x4 hv = {h0, h1, h2, h3};
        bf16x4 lv = {(bf16_t)(v.x - (float)h0), (bf16_t)(v.y - (float)h1),
                     (bf16_t)(v.z - (float)h2), (bf16_t)(v.w - (float)h3)};
        *(bf16x4*)&Whi[r * WP + 4 * c4] = hv;
        *(bf16x4*)&Wlo[r * WP + 4 * c4] = lv;
    }

    // A fragments from global (hi/lo)
    const int w = t >> 6, l = t & 63;
    const int mrow = l & 15, kq = l >> 4;
    const int gn = base + 16 * w + mrow;
    bf16x8 ahi[4], alo[4];
    {
        const float4* xr4 = (const float4*)(x + (size_t)gn * 128);
#pragma unroll
        for (int kt = 0; kt < 4; ++kt) {
            float4 v0 = make_float4(0.f, 0.f, 0.f, 0.f), v1 = v0;
            if (gn < N) {
                v0 = xr4[8 * kt + 2 * kq];
                v1 = xr4[8 * kt + 2 * kq + 1];
            }
            float f[8] = {v0.x, v0.y, v0.z, v0.w, v1.x, v1.y, v1.z, v1.w};
#pragma unroll
            for (int i = 0; i < 8; ++i) {
                bf16_t h = (bf16_t)f[i];
                ahi[kt][i] = h;
                alo[kt][i] = (bf16_t)(f[i] - (float)h);
            }
        }
    }
    __syncthreads();

    f32x4 acc[8];
#pragma unroll
    for (int nt = 0; nt < 8; ++nt) acc[nt] = (f32x4){0.f, 0.f, 0.f, 0.f};

#pragma unroll
    for (int nt = 0; nt < 8; ++nt) {
#pragma unroll
        for (int kt = 0; kt < 4; ++kt) {
            bf16x8 bhi = *(bf16x8*)&Whi[(16 * nt + mrow) * WP + 32 * kt + 8 * kq];
            bf16x8 blo = *(bf16x8*)&Wlo[(16 * nt + mrow) * WP + 32 * kt + 8 * kq];
            acc[nt] = __builtin_amdgcn_mfma_f32_16x16x32_bf16(ahi[kt], bhi, acc[nt], 0, 0, 0);
            acc[nt] = __builtin_amdgcn_mfma_f32_16x16x32_bf16(alo[kt], bhi, acc[nt], 0, 0, 0);
            acc[nt] = __builtin_amdgcn_mfma_f32_16x16x32_bf16(ahi[kt], blo, acc[nt], 0, 0, 0);
        }
    }
    __syncthreads();  // all waves done reading W before overlay

    // write h to LDS overlay, re-map to 4 threads/node
#pragma unroll
    for (int nt = 0; nt < 8; ++nt)
#pragma unroll
        for (int r = 0; r < 4; ++r)
            h_s[(16 * w + 4 * kq + r) * HP + 16 * nt + mrow] = acc[nt][r];
    __syncthreads();

    const int node = t >> 2, lg = t & 3;
    const int gn2 = base + node;
    float h[32], hb[32];
#pragma unroll
    for (int q = 0; q < 8; ++q) {
        float4 v = *(const float4*)&h_s[node * HP + lg * 32 + 4 * q];
        h[4 * q] = v.x; h[4 * q + 1] = v.y; h[4 * q + 2] = v.z; h[4 * q + 3] = v.w;
        float4 b = *(const float4*)&hb_s[lg * 32 + 4 * q];
        hb[4 * q] = b.x; hb[4 * q + 1] = b.y; hb[4 * q + 2] = b.z; hb[4 * q + 3] = b.w;
    }
    // proj(h)
    float x2 = 0.f;
#pragma unroll
    for (int d = 0; d < 32; ++d) x2 += h[d] * h[d];
    x2 += __shfl_xor(x2, 1); x2 += __shfl_xor(x2, 2);
    float nrm = sqrtf(x2);
    float sc = nrm > MAXN ? MAXN / nrm : 1.f;
#pragma unroll
    for (int d = 0; d < 32; ++d) h[d] *= sc;
    x2 *= sc * sc;
    // mobius_add(h, hb)
    float xy = 0.f;
#pragma unroll
    for (int d = 0; d < 32; ++d) xy += h[d] * hb[d];
    xy += __shfl_xor(xy, 1); xy += __shfl_xor(xy, 2);
    float ca = 1.f + 2.f * xy + y2;
    float cb = 1.f - x2;
    float den = 1.f + 2.f * xy + x2 * y2;
    float invd = 1.f / fmaxf(den, MINN);
    float m2 = 0.f;
#pragma unroll
    for (int d = 0; d < 32; ++d) {
        float v = (ca * h[d] + cb * hb[d]) * invd;
        h[d] = v;
        m2 += v * v;
    }
    m2 += __shfl_xor(m2, 1); m2 += __shfl_xor(m2, 2);
    // proj again
    float nrm2 = sqrtf(m2);
    float sc2 = nrm2 > MAXN ? MAXN / nrm2 : 1.f;
    m2 *= sc2 * sc2;
    // p2k + lorenz
    float pf = 2.f / (1.f + m2);
    float ns = pf * pf * m2;
    float lamb = rsqrtf(fmaxf(1.f - ns, MINN));
    if (gn2 < N) {
        bf16_t* dst = sbuf + (size_t)gn2 * 128 + lg * 32;
        float f = pf * sc2;
#pragma unroll
        for (int q = 0; q < 4; ++q) {
            bf16x8 sv;
#pragma unroll
            for (int j = 0; j < 8; ++j) sv[j] = (bf16_t)(f * h[8 * q + j]);
            *(bf16x8*)&dst[8 * q] = sv;
        }
        if (lg == 0) {
            nsbuf[gn2] = ns;  // exact f32 ||s||^2 (rescues deg-0 nodes in k_agg)
            gbuf[gn2] = lamb * rsqrtf((float)(cnt[gn2] + 1));
        }
    }
}

// ---------------- aggregation + k2p + leaky_relu ----------------
// one wave per node. Per 64-edge batch: lane preloads index jv AND weight gv;
// tw via one wave-reduce; gather loop BRANCHLESS, 16 edges/iter via quarter-
// waves: 16 lanes x bf16x8 (16 B) = one full 256 B row per edge, 4 loads/lane
// in flight. Tail lanes: jv=0, gv=0 -> gather row 0 (hot), FMA by 0 (exact).
// deg-0 nodes use the stored f32 ns (k2p amplifies ns error ~150x there).
// NOTE: __shfl must execute with FULL exec (R3 bug).
__global__ __launch_bounds__(256) void k_agg(const bf16_t* __restrict__ s,
                                             const float* __restrict__ nsb,
                                             const float* __restrict__ g,
                                             const int* __restrict__ rowst,
                                             const int* __restrict__ cnt,
                                             const int* __restrict__ csr,
                                             float* __restrict__ out, int N) {
    const int wid = threadIdx.x >> 6, lane = threadIdx.x & 63;
    const int q = lane >> 4, ql = lane & 15;
    const int i = blockIdx.x * 4 + wid;
    if (i >= N) return;

    float a[8] = {0.f, 0.f, 0.f, 0.f, 0.f, 0.f, 0.f, 0.f};
    float tw = g[i];  // self-loop weight (all lanes)
    if (q == 0) {     // self-loop vector term on quarter 0 (counted once)
        bf16x8 sv = *(const bf16x8*)(s + (size_t)i * 128 + ql * 8);
#pragma unroll
        for (int d = 0; d < 8; ++d) a[d] = tw * (float)sv[d];
    }
    const int st = rowst[i];
    const int c = cnt[i];
    for (int bs = 0; bs < c; bs += 64) {
        int rem = c - bs;
        if (rem > 64) rem = 64;
        int jv = 0;
        float gv = 0.f;
        if (lane < rem) {
            jv = csr[st + bs + lane];
            gv = g[jv];
        }
        // batch weight sum (one reduce instead of per-edge accumulation)
        float tws = gv;
#pragma unroll
        for (int m = 1; m < 64; m <<= 1) tws += __shfl_xor(tws, m);
        tw += tws;
        for (int e = 0; e < rem; e += 16) {
            // e <= 48, q <= 3 -> all source lanes <= 63; full-exec shfl
            int j0 = __shfl(jv, e + q);
            int j1 = __shfl(jv, e + 4 + q);
            int j2 = __shfl(jv, e + 8 + q);
            int j3 = __shfl(jv, e + 12 + q);
            float g0 = __shfl(gv, e + q);
            float g1 = __shfl(gv, e + 4 + q);
            float g2 = __shfl(gv, e + 8 + q);
            float g3 = __shfl(gv, e + 12 + q);
            bf16x8 v0 = *(const bf16x8*)(s + (size_t)j0 * 128 + ql * 8);
            bf16x8 v1 = *(const bf16x8*)(s + (size_t)j1 * 128 + ql * 8);
            bf16x8 v2 = *(const bf16x8*)(s + (size_t)j2 * 128 + ql * 8);
            bf16x8 v3 = *(const bf16x8*)(s + (size_t)j3 * 128 + ql * 8);
#pragma unroll
            for (int d = 0; d < 8; ++d) {
                a[d] = fmaf(g0, (float)v0[d], a[d]);
                a[d] = fmaf(g1, (float)v1[d], a[d]);
                a[d] = fmaf(g2, (float)v2[d], a[d]);
                a[d] = fmaf(g3, (float)v3[d], a[d]);
            }
        }
    }
    // combine the 4 quarter-wave partial sums (lanes with equal ql)
#pragma unroll
    for (int d = 0; d < 8; ++d) {
        a[d] += __shfl_xor(a[d], 16);
        a[d] += __shfl_xor(a[d], 32);
    }

    float inv = 1.f / tw;
    float o[8];
    float ns = 0.f;
#pragma unroll
    for (int d = 0; d < 8; ++d) {
        o[d] = a[d] * inv;
        ns += o[d] * o[d];
    }
    // sum over the 16 ql positions (quarters already hold identical values)
    ns += __shfl_xor(ns, 1); ns += __shfl_xor(ns, 2);
    ns += __shfl_xor(ns, 4); ns += __shfl_xor(ns, 8);
    if (c == 0) ns = nsb[i];  // exact f32 norm for isolated nodes (uniform branch)
    float den = 1.f + sqrtf(fmaxf(1.f - ns, MINN));
    float id = 1.f / den;
#pragma unroll
    for (int d = 0; d < 8; ++d) {
        float v = o[d] * id;
        o[d] = v >= 0.f ? v : 0.01f * v;
    }
    if (lane < 32) {  // 32 lanes x 16B = full 512B coalesced row store
        float4 v = make_float4(o[4 * q], o[4 * q + 1], o[4 * q + 2], o[4 * q + 3]);
        *(float4*)(out + (size_t)i * 128 + ql * 8 + 4 * q) = v;
    }
}

extern "C" void kernel_launch(void* const* d_in, const int* in_sizes, int n_in,
                              void* d_out, int out_size, void* d_ws, size_t ws_size,
                              hipStream_t stream) {
    const float* x    = (const float*)d_in[0];
    const float* W    = (const float*)d_in[1];
    const float* bias = (const float*)d_in[2];
    const int*   ei   = (const int*)d_in[3];  // [2,E] int32

    const int N = in_sizes[0] / 128;
    const int E = in_sizes[3] / 2;
    const int* row = ei;
    const int* col = ei + E;

    // workspace carve (~35 MB)
    float*  g_buf  = (float*)d_ws;                 // N
    float*  ns_buf = g_buf + N;                    // N
    int*    cnt    = (int*)(ns_buf + N);           // N
    int*    rowst  = cnt + N;                      // N
    int*    pos    = rowst + N;                    // E
    int*    csr    = pos + E;                      // E
    int*    bsum   = csr + E;                      // <=128
    bf16_t* s_buf  = (bf16_t*)(bsum + 128);        // N*128 bf16

    hipMemsetAsync(cnt, 0, (size_t)N * sizeof(int), stream);

    const int nb = (N + 1023) / 1024;  // 98 <= 128
    k_deg2<<<(E + 255) / 256, 256, 0, stream>>>(row, cnt, pos, E);
    k_bsum<<<nb, 1024, 0, stream>>>(cnt, bsum, N);
    k_scan_bsum<<<1, 128, 0, stream>>>(bsum, nb);
    k_rowstart<<<nb, 1024, 0, stream>>>(cnt, bsum, rowst, N);
    k_place<<<(E + 255) / 256, 256, 0, stream>>>(row, col, rowst, pos, csr, E);
    k_gemm<<<(N + 63) / 64, 256, 0, stream>>>(x, W, bias, cnt, s_buf, ns_buf,
                                              g_buf, N);
    k_agg<<<(N + 3) / 4, 256, 0, stream>>>(s_buf, ns_buf, g_buf, rowst, cnt, csr,
                                           (float*)d_out, N);
}

// Round 9
// 154.586 us; speedup vs baseline: 1.3104x; 1.2074x over previous
//
#include <hip/hip_runtime.h>
#include <math.h>

// Hyperbolic GCN conv (Poincare ball, c=1):
//  h = proj(x W^T); h = proj(mobius_add(h, expmap0(bias)))
//  s = p2k(h); lamb = lorenz(s); g = deg^-1/2 * lamb
//  s_out[i] = (sum_{j in N(i)+self} g[j] s[j]) / (sum g[j])   [dinv[i] cancels]
//  out = leaky_relu(k2p(s_out))
// s stored in BF16 for the gather; deg-0 nodes use a per-node f32 ns from
// k_gemm (k2p amplifies ns error ~150x only when s_out == s_i, ns ~ 0.9999).
// k_agg: QUARTER-WAVE per node (R8 post-mortem: latency-bound, not BW-bound;
// 4 nodes/wave quadruples independent memory streams per wave slot).

#define EPS_B 4e-3f
#define MINN 1e-15f

typedef __bf16 bf16_t;
typedef __attribute__((ext_vector_type(8))) __bf16 bf16x8;
typedef __attribute__((ext_vector_type(4))) __bf16 bf16x4;
typedef __attribute__((ext_vector_type(4))) float f32x4;

// ---------------- degree + slot in one atomic pass ----------------
__global__ __launch_bounds__(256) void k_deg2(const int* __restrict__ row,
                                              int* __restrict__ cnt,
                                              int* __restrict__ pos, int E) {
    int e = blockIdx.x * 256 + threadIdx.x;
    if (e < E) pos[e] = atomicAdd(&cnt[row[e]], 1);
}

// ---------------- scan (3 kernels, 1024-wide) ----------------
__global__ __launch_bounds__(1024) void k_bsum(const int* __restrict__ cnt,
                                               int* __restrict__ bsum, int n) {
    __shared__ int sd[1024];
    int t = threadIdx.x, idx = blockIdx.x * 1024 + t;
    sd[t] = idx < n ? cnt[idx] : 0;
    __syncthreads();
    for (int s = 512; s > 0; s >>= 1) {
        if (t < s) sd[t] += sd[t + s];
        __syncthreads();
    }
    if (t == 0) bsum[blockIdx.x] = sd[0];
}

__global__ __launch_bounds__(128) void k_scan_bsum(int* bsum, int nb) {
    __shared__ int sd[128];
    int t = threadIdx.x;
    int v = t < nb ? bsum[t] : 0;
    sd[t] = v;
    __syncthreads();
    for (int off = 1; off < 128; off <<= 1) {
        int x = (t >= off) ? sd[t - off] : 0;
        __syncthreads();
        sd[t] += x;
        __syncthreads();
    }
    if (t < nb) bsum[t] = sd[t] - v;  // exclusive
}

__global__ __launch_bounds__(1024) void k_rowstart(const int* __restrict__ cnt,
                                                   const int* __restrict__ bsum,
                                                   int* __restrict__ rowst, int n) {
    __shared__ int sd[1024];
    int t = threadIdx.x, idx = blockIdx.x * 1024 + t;
    int v = idx < n ? cnt[idx] : 0;
    sd[t] = v;
    __syncthreads();
    for (int off = 1; off < 1024; off <<= 1) {
        int x = (t >= off) ? sd[t - off] : 0;
        __syncthreads();
        sd[t] += x;
        __syncthreads();
    }
    if (idx < n) rowst[idx] = sd[t] - v + bsum[blockIdx.x];
}

// ---------------- CSR placement (no atomics) ----------------
__global__ __launch_bounds__(256) void k_place(const int* __restrict__ row,
                                               const int* __restrict__ col,
                                               const int* __restrict__ rowst,
                                               const int* __restrict__ pos,
                                               int* __restrict__ csr, int E) {
    int e = blockIdx.x * 256 + threadIdx.x;
    if (e < E) csr[rowst[row[e]] + pos[e]] = col[e];
}

// ---------------- GEMM (split-bf16 MFMA) + hyperbolic transforms ----------------
// R4-proven structure: W hi/lo staged in LDS as bf16 [128][136] per block.
// mfma_f32_16x16x32_bf16: A lane l holds A[l&15][8*(l>>4)+i];
// B lane l holds B[8*(l>>4)+i][l&15]; D lane l reg r holds D[4*(l>>4)+r][l&15].
#define WP 136  // bf16 pitch for W tiles
#define HP 140  // f32 pitch for h overlay

__global__ __launch_bounds__(256, 2) void k_gemm(const float* __restrict__ x,
                                                 const float* __restrict__ W,
                                                 const float* __restrict__ bias,
                                                 const int* __restrict__ cnt,
                                                 bf16_t* __restrict__ sbuf,
                                                 float* __restrict__ nsbuf,
                                                 float* __restrict__ gbuf, int N) {
    __shared__ __align__(16) unsigned char smem[128 * WP * 2 * 2];  // 69632 B
    bf16_t* Whi = (bf16_t*)smem;
    bf16_t* Wlo = Whi + 128 * WP;
    float* h_s = (float*)smem;  // overlay after MFMA: [64][HP] f32 = 35840 B
    __shared__ float hb_s[128];

    const int t = threadIdx.x;
    const int base = blockIdx.x * 64;
    const float MAXN = 1.0f - EPS_B;

    // hyp bias = expmap0(bias); ||b||^2 via 2 reads + wave shfl reduce
    if (t < 128) hb_s[t] = bias[t];
    __syncthreads();
    const int l6 = t & 63;
    float b0 = hb_s[2 * l6], b1 = hb_s[2 * l6 + 1];
    float bn2 = b0 * b0 + b1 * b1;
#pragma unroll
    for (int m = 1; m < 64; m <<= 1) bn2 += __shfl_xor(bn2, m);
    float un = fmaxf(sqrtf(bn2), MINN);
    float th = tanhf(un);
    float y2 = th * th;
    __syncthreads();  // all bn2 reads done before rescale
    if (t < 128) hb_s[t] *= th / un;

    // stage W as hi/lo bf16
#pragma unroll
    for (int i2 = 0; i2 < 16; ++i2) {
        int idx = t + 256 * i2;  // 0..4095 float4s
        int r = idx >> 5, c4 = idx & 31;
        float4 v = ((const float4*)W)[idx];
        bf16_t h0 = (bf16_t)v.x, h1 = (bf16_t)v.y, h2 = (bf16_t)v.z, h3 = (bf16_t)v.w;
        bf16x4 hv = {h0, h1, h2, h3};
        bf16x4 lv = {(bf16_t)(v.x - (float)h0), (bf16_t)(v.y - (float)h1),
                     (bf16_t)(v.z - (float)h2), (bf16_t)(v.w - (float)h3)};
        *(bf16x4*)&Whi[r * WP + 4 * c4] = hv;
        *(bf16x4*)&Wlo[r * WP + 4 * c4] = lv;
    }

    // A fragments from global (hi/lo)
    const int w = t >> 6, l = t & 63;
    const int mrow = l & 15, kq = l >> 4;
    const int gn = base + 16 * w + mrow;
    bf16x8 ahi[4], alo[4];
    {
        const float4* xr4 = (const float4*)(x + (size_t)gn * 128);
#pragma unroll
        for (int kt = 0; kt < 4; ++kt) {
            float4 v0 = make_float4(0.f, 0.f, 0.f, 0.f), v1 = v0;
            if (gn < N) {
                v0 = xr4[8 * kt + 2 * kq];
                v1 = xr4[8 * kt + 2 * kq + 1];
            }
            float f[8] = {v0.x, v0.y, v0.z, v0.w, v1.x, v1.y, v1.z, v1.w};
#pragma unroll
            for (int i = 0; i < 8; ++i) {
                bf16_t h = (bf16_t)f[i];
                ahi[kt][i] = h;
                alo[kt][i] = (bf16_t)(f[i] - (float)h);
            }
        }
    }
    __syncthreads();

    f32x4 acc[8];
#pragma unroll
    for (int nt = 0; nt < 8; ++nt) acc[nt] = (f32x4){0.f, 0.f, 0.f, 0.f};

#pragma unroll
    for (int nt = 0; nt < 8; ++nt) {
#pragma unroll
        for (int kt = 0; kt < 4; ++kt) {
            bf16x8 bhi = *(bf16x8*)&Whi[(16 * nt + mrow) * WP + 32 * kt + 8 * kq];
            bf16x8 blo = *(bf16x8*)&Wlo[(16 * nt + mrow) * WP + 32 * kt + 8 * kq];
            acc[nt] = __builtin_amdgcn_mfma_f32_16x16x32_bf16(ahi[kt], bhi, acc[nt], 0, 0, 0);
            acc[nt] = __builtin_amdgcn_mfma_f32_16x16x32_bf16(alo[kt], bhi, acc[nt], 0, 0, 0);
            acc[nt] = __builtin_amdgcn_mfma_f32_16x16x32_bf16(ahi[kt], blo, acc[nt], 0, 0, 0);
        }
    }
    __syncthreads();  // all waves done reading W before overlay

    // write h to LDS overlay, re-map to 4 threads/node
#pragma unroll
    for (int nt = 0; nt < 8; ++nt)
#pragma unroll
        for (int r = 0; r < 4; ++r)
            h_s[(16 * w + 4 * kq + r) * HP + 16 * nt + mrow] = acc[nt][r];
    __syncthreads();

    const int node = t >> 2, lg = t & 3;
    const int gn2 = base + node;
    float h[32], hb[32];
#pragma unroll
    for (int q = 0; q < 8; ++q) {
        float4 v = *(const float4*)&h_s[node * HP + lg * 32 + 4 * q];
        h[4 * q] = v.x; h[4 * q + 1] = v.y; h[4 * q + 2] = v.z; h[4 * q + 3] = v.w;
        float4 b = *(const float4*)&hb_s[lg * 32 + 4 * q];
        hb[4 * q] = b.x; hb[4 * q + 1] = b.y; hb[4 * q + 2] = b.z; hb[4 * q + 3] = b.w;
    }
    // proj(h)
    float x2 = 0.f;
#pragma unroll
    for (int d = 0; d < 32; ++d) x2 += h[d] * h[d];
    x2 += __shfl_xor(x2, 1); x2 += __shfl_xor(x2, 2);
    float nrm = sqrtf(x2);
    float sc = nrm > MAXN ? MAXN / nrm : 1.f;
#pragma unroll
    for (int d = 0; d < 32; ++d) h[d] *= sc;
    x2 *= sc * sc;
    // mobius_add(h, hb)
    float xy = 0.f;
#pragma unroll
    for (int d = 0; d < 32; ++d) xy += h[d] * hb[d];
    xy += __shfl_xor(xy, 1); xy += __shfl_xor(xy, 2);
    float ca = 1.f + 2.f * xy + y2;
    float cb = 1.f - x2;
    float den = 1.f + 2.f * xy + x2 * y2;
    float invd = 1.f / fmaxf(den, MINN);
    float m2 = 0.f;
#pragma unroll
    for (int d = 0; d < 32; ++d) {
        float v = (ca * h[d] + cb * hb[d]) * invd;
        h[d] = v;
        m2 += v * v;
    }
    m2 += __shfl_xor(m2, 1); m2 += __shfl_xor(m2, 2);
    // proj again
    float nrm2 = sqrtf(m2);
    float sc2 = nrm2 > MAXN ? MAXN / nrm2 : 1.f;
    m2 *= sc2 * sc2;
    // p2k + lorenz
    float pf = 2.f / (1.f + m2);
    float ns = pf * pf * m2;
    float lamb = rsqrtf(fmaxf(1.f - ns, MINN));
    if (gn2 < N) {
        bf16_t* dst = sbuf + (size_t)gn2 * 128 + lg * 32;
        float f = pf * sc2;
#pragma unroll
        for (int q = 0; q < 4; ++q) {
            bf16x8 sv;
#pragma unroll
            for (int j = 0; j < 8; ++j) sv[j] = (bf16_t)(f * h[8 * q + j]);
            *(bf16x8*)&dst[8 * q] = sv;
        }
        if (lg == 0) {
            nsbuf[gn2] = ns;  // exact f32 ||s||^2 (rescues deg-0 nodes in k_agg)
            gbuf[gn2] = lamb * rsqrtf((float)(cnt[gn2] + 1));
        }
    }
}

// ---------------- aggregation + k2p + leaky_relu ----------------
// QUARTER-WAVE (16 lanes) per node: 4 nodes per wave, 16 per block.
// Per node: scalar loads + csr/g preload issue in the same wave instructions
// for all 4 nodes (4x memory-level parallelism per dependent latency round);
// gather = 16 lanes x bf16x8 = one full 256 B row per load instruction,
// 4-deep branchless unroll (tail: jv=0,gv=0 -> row-0 gather, fma by 0).
// All __shfl sources lie in the reader's own quarter, which is active at the
// read point (R3 rule). Cross-quarter combines eliminated entirely.
__global__ __launch_bounds__(256) void k_agg(const bf16_t* __restrict__ s,
                                             const float* __restrict__ nsb,
                                             const float* __restrict__ g,
                                             const int* __restrict__ rowst,
                                             const int* __restrict__ cnt,
                                             const int* __restrict__ csr,
                                             float* __restrict__ out, int N) {
    const int lane = threadIdx.x & 63, wid = threadIdx.x >> 6;
    const int q = lane >> 4, ql = lane & 15;
    const int i = blockIdx.x * 16 + wid * 4 + q;
    const bool valid = i < N;
    const int ic = valid ? i : 0;

    const int st = rowst[ic];
    const int c = valid ? cnt[ic] : 0;
    const float gi = g[ic];

    // self-loop term (full row held by the quarter)
    float a[8];
    {
        bf16x8 sv = *(const bf16x8*)(s + (size_t)ic * 128 + ql * 8);
#pragma unroll
        for (int d = 0; d < 8; ++d) a[d] = gi * (float)sv[d];
    }
    float gvs = 0.f;  // per-lane neighbor-weight partial (reduced at end)

    for (int bs = 0; bs < c; bs += 16) {
        int rem = c - bs;
        if (rem > 16) rem = 16;
        int jv = 0;
        float gv = 0.f;
        if (ql < rem) {
            jv = csr[st + bs + ql];
            gv = g[jv];
        }
        gvs += gv;
        for (int e = 0; e < rem; e += 4) {  // e in {0,4,8,12}; sources ql<=15 in own quarter
            int j0 = __shfl(jv, 16 * q + e);
            int j1 = __shfl(jv, 16 * q + e + 1);
            int j2 = __shfl(jv, 16 * q + e + 2);
            int j3 = __shfl(jv, 16 * q + e + 3);
            float g0 = __shfl(gv, 16 * q + e);
            float g1 = __shfl(gv, 16 * q + e + 1);
            float g2 = __shfl(gv, 16 * q + e + 2);
            float g3 = __shfl(gv, 16 * q + e + 3);
            bf16x8 v0 = *(const bf16x8*)(s + (size_t)j0 * 128 + ql * 8);
            bf16x8 v1 = *(const bf16x8*)(s + (size_t)j1 * 128 + ql * 8);
            bf16x8 v2 = *(const bf16x8*)(s + (size_t)j2 * 128 + ql * 8);
            bf16x8 v3 = *(const bf16x8*)(s + (size_t)j3 * 128 + ql * 8);
#pragma unroll
            for (int d = 0; d < 8; ++d) {
                a[d] = fmaf(g0, (float)v0[d], a[d]);
                a[d] = fmaf(g1, (float)v1[d], a[d]);
                a[d] = fmaf(g2, (float)v2[d], a[d]);
                a[d] = fmaf(g3, (float)v3[d], a[d]);
            }
        }
    }
    // neighbor-weight sum within the quarter (xor 1,2,4,8 stays in-quarter)
    gvs += __shfl_xor(gvs, 1); gvs += __shfl_xor(gvs, 2);
    gvs += __shfl_xor(gvs, 4); gvs += __shfl_xor(gvs, 8);
    float tw = gi + gvs;

    float inv = 1.f / tw;
    float o[8];
    float ns = 0.f;
#pragma unroll
    for (int d = 0; d < 8; ++d) {
        o[d] = a[d] * inv;
        ns += o[d] * o[d];
    }
    ns += __shfl_xor(ns, 1); ns += __shfl_xor(ns, 2);
    ns += __shfl_xor(ns, 4); ns += __shfl_xor(ns, 8);
    if (c == 0) ns = nsb[ic];  // exact f32 norm for isolated nodes
    float den = 1.f + sqrtf(fmaxf(1.f - ns, MINN));
    float id = 1.f / den;
#pragma unroll
    for (int d = 0; d < 8; ++d) {
        float v = o[d] * id;
        o[d] = v >= 0.f ? v : 0.01f * v;
    }
    if (valid) {  // 16 lanes x 32 B = full 512 B row, coalesced per quarter
        float* dst = out + (size_t)i * 128 + ql * 8;
        *(float4*)dst = make_float4(o[0], o[1], o[2], o[3]);
        *(float4*)(dst + 4) = make_float4(o[4], o[5], o[6], o[7]);
    }
}

extern "C" void kernel_launch(void* const* d_in, const int* in_sizes, int n_in,
                              void* d_out, int out_size, void* d_ws, size_t ws_size,
                              hipStream_t stream) {
    const float* x    = (const float*)d_in[0];
    const float* W    = (const float*)d_in[1];
    const float* bias = (const float*)d_in[2];
    const int*   ei   = (const int*)d_in[3];  // [2,E] int32

    const int N = in_sizes[0] / 128;
    const int E = in_sizes[3] / 2;
    const int* row = ei;
    const int* col = ei + E;

    // workspace carve (~35 MB)
    float*  g_buf  = (float*)d_ws;                 // N
    float*  ns_buf = g_buf + N;                    // N
    int*    cnt    = (int*)(ns_buf + N);           // N
    int*    rowst  = cnt + N;                      // N
    int*    pos    = rowst + N;                    // E
    int*    csr    = pos + E;                      // E
    int*    bsum   = csr + E;                      // <=128
    bf16_t* s_buf  = (bf16_t*)(bsum + 128);        // N*128 bf16

    hipMemsetAsync(cnt, 0, (size_t)N * sizeof(int), stream);

    const int nb = (N + 1023) / 1024;  // 98 <= 128
    k_deg2<<<(E + 255) / 256, 256, 0, stream>>>(row, cnt, pos, E);
    k_bsum<<<nb, 1024, 0, stream>>>(cnt, bsum, N);
    k_scan_bsum<<<1, 128, 0, stream>>>(bsum, nb);
    k_rowstart<<<nb, 1024, 0, stream>>>(cnt, bsum, rowst, N);
    k_place<<<(E + 255) / 256, 256, 0, stream>>>(row, col, rowst, pos, csr, E);
    k_gemm<<<(N + 63) / 64, 256, 0, stream>>>(x, W, bias, cnt, s_buf, ns_buf,
                                              g_buf, N);
    k_agg<<<(N + 15) / 16, 256, 0, stream>>>(s_buf, ns_buf, g_buf, rowst, cnt, csr,
                                             (float*)d_out, N);
}